// Round 19
// baseline (157.628 us; speedup 1.0000x reference)
//
#include <hip/hip_runtime.h>

typedef unsigned short u16;
typedef __attribute__((ext_vector_type(8))) short bf16x8;
typedef __attribute__((ext_vector_type(4))) float f32x4;
typedef __attribute__((ext_vector_type(4))) unsigned short u16x4;

#define MFMA16 __builtin_amdgcn_mfma_f32_16x16x32_bf16

__device__ __forceinline__ u16 f2bf(float f) {
  unsigned int u = __float_as_uint(f);
  u += 0x7fff + ((u >> 16) & 1);          // round-to-nearest-even
  return (u16)(u >> 16);
}

__device__ __forceinline__ float vexp2(float x) {
  float r; asm("v_exp_f32 %0, %1" : "=v"(r) : "v"(x)); return r;
}

// DPP lane-permute within 16-lane rows (VALU-latency)
template<int CTRL>
__device__ __forceinline__ float dppf(float v) {
  return __int_as_float(__builtin_amdgcn_update_dpp(0, __float_as_int(v), CTRL, 0xF, 0xF, true));
}
__device__ __forceinline__ float rowsum16(float v) {
  v += dppf<0xB1>(v);
  v += dppf<0x4E>(v);
  v += dppf<0x141>(v);
  v += dppf<0x140>(v);
  return v;
}

__device__ __forceinline__ void gload_lds16(const void* g, void* l) {
  __builtin_amdgcn_global_load_lds((__attribute__((address_space(1))) void*)g,
                                   (__attribute__((address_space(3))) void*)l,
                                   16, 0, 0);
}

// ---------------- fused prep: cast x + transpose both weights ----------------
__global__ void k_prep(const float* __restrict__ x, u16* __restrict__ x_bf,
                       const float* __restrict__ w_attn, u16* __restrict__ wa_t,
                       const float* __restrict__ w_proj, u16* __restrict__ wp_t) {
  __shared__ float tile[64][65];
  const int blk = blockIdx.x;
  const int t = threadIdx.x;
  if (blk < 5120) {
    const int i = blk * 256 + t;
    const float4 v = reinterpret_cast<const float4*>(x)[i];
    u16x4 o = {f2bf(v.x), f2bf(v.y), f2bf(v.z), f2bf(v.w)};
    reinterpret_cast<u16x4*>(x_bf)[i] = o;
    return;
  }
  const float* src;
  u16* dst;
  int R, C, c0, r0;
  if (blk < 6320) {
    const int id = blk - 5120;
    src = w_attn; dst = wa_t; R = 1280; C = 3840;
    c0 = (id % 60) * 64; r0 = (id / 60) * 64;
  } else {
    const int id = blk - 6320;
    src = w_proj; dst = wp_t; R = 1280; C = 1280;
    c0 = (id % 20) * 64; r0 = (id / 20) * 64;
  }
#pragma unroll
  for (int i = 0; i < 16; ++i) {
    int e = i * 256 + t;
    int r = e >> 6, c = e & 63;
    tile[r][c] = src[(size_t)(r0 + r) * C + (c0 + c)];
  }
  __syncthreads();
#pragma unroll
  for (int i = 0; i < 16; ++i) {
    int e = i * 256 + t;
    int r = e >> 6, c = e & 63;
    dst[(size_t)(c0 + r) * R + (r0 + c)] = f2bf(tile[c][r]);
  }
}

// ---------------- qkv GEMM v2: 64x128 tile, double-buffered, overlap staging ----------
// Q,K written as [bh][s][64]; V written TRANSPOSED as VT [bh][d][2048].
// dbuf 48KB -> 3 blocks/CU; stage(t+1) issued BEFORE compute(t) so its drain
// hides under the MFMAs (round-16 structure at champion occupancy).
__global__ __launch_bounds__(256, 3) void k_gemm_qkv(
    const u16* __restrict__ A, const u16* __restrict__ Bt,
    const float* __restrict__ bias,
    u16* __restrict__ qo, u16* __restrict__ ko, u16* __restrict__ vt) {
  constexpr int K = 1280;
  __shared__ u16 Alds[2][64 * 64];
  __shared__ u16 Blds[2][128 * 64];
  const int t = threadIdx.x;
  const int lane = t & 63, wave = t >> 6;
  const int wr = wave >> 1, wc = wave & 1;
  const int l15 = lane & 15, lhi = lane >> 4;
  const int m0 = blockIdx.x * 64, n0 = blockIdx.y * 128;

  f32x4 acc[2][4];
#pragma unroll
  for (int mi = 0; mi < 2; ++mi)
#pragma unroll
    for (int ni = 0; ni < 4; ++ni) acc[mi][ni] = f32x4{0.f, 0.f, 0.f, 0.f};

  const int srow = t >> 3;
  const int scol = (t & 7) * 8;
  const u16* Ag = A + (size_t)(m0 + srow) * K + scol;
  const u16* Bg = Bt + (size_t)(n0 + srow) * K + scol;

  auto stage = [&](int buf, int k0) {
    char* Al = (char*)Alds[buf] + wave * 1024;
    char* Bl = (char*)Blds[buf] + wave * 1024;
#pragma unroll
    for (int it = 0; it < 2; ++it)
      gload_lds16(Ag + (it * 32) * K + k0, Al + it * 4096);
#pragma unroll
    for (int it = 0; it < 4; ++it)
      gload_lds16(Bg + (it * 32) * K + k0, Bl + it * 4096);
  };

  stage(0, 0);
  asm volatile("s_waitcnt vmcnt(0)" ::: "memory");
  __syncthreads();

  int cur = 0;
  for (int k0 = 0; k0 < K; k0 += 64) {
    if (k0 + 64 < K) stage(cur ^ 1, k0 + 64);   // issue next tile BEFORE compute
    const u16* Ab = Alds[cur] + (wr * 32 + l15) * 64 + lhi * 8;
    const u16* Bb = Blds[cur] + (wc * 64 + l15) * 64 + lhi * 8;
    bf16x8 af[2][2], bfv[4][2];
#pragma unroll
    for (int x = 0; x < 2; ++x) {
      af[x][0] = *(const bf16x8*)(Ab + x * 1024);
      af[x][1] = *(const bf16x8*)(Ab + x * 1024 + 32);
    }
#pragma unroll
    for (int x = 0; x < 4; ++x) {
      bfv[x][0] = *(const bf16x8*)(Bb + x * 1024);
      bfv[x][1] = *(const bf16x8*)(Bb + x * 1024 + 32);
    }
#pragma unroll
    for (int mi = 0; mi < 2; ++mi)
#pragma unroll
      for (int ni = 0; ni < 4; ++ni) {
        acc[mi][ni] = MFMA16(af[mi][0], bfv[ni][0], acc[mi][ni], 0, 0, 0);
        acc[mi][ni] = MFMA16(af[mi][1], bfv[ni][1], acc[mi][ni], 0, 0, 0);
      }
    asm volatile("s_waitcnt vmcnt(0)" ::: "memory");
    __syncthreads();
    cur ^= 1;
  }

  const int which = n0 >= 2560 ? 2 : (n0 >= 1280 ? 1 : 0);
  const int bbq = m0 >> 11;                // batch index (constant per block)
  const int sbase = (m0 & 2047) + wr * 32; // s offset of this wave's rows
  if (which < 2) {
    u16* outp = which == 0 ? qo : ko;
#pragma unroll
    for (int ni = 0; ni < 4; ++ni) {
      const int n_abs = n0 + wc * 64 + ni * 16 + l15;
      const int nn = n_abs - which * 1280;
      const int h = nn >> 6, d = nn & 63;
      const float bv = bias[n_abs];
#pragma unroll
      for (int mi = 0; mi < 2; ++mi) {
#pragma unroll
        for (int i = 0; i < 4; ++i) {
          const int ss = sbase + mi * 16 + lhi * 4 + i;
          outp[(((size_t)(bbq * 20 + h) * 2048 + ss) << 6) + d] = f2bf(acc[mi][ni][i] + bv);
        }
      }
    }
  } else {
    // V: write transposed VT[(bb*20+h)*64 + d][s], 4 consecutive s -> 8B store
#pragma unroll
    for (int ni = 0; ni < 4; ++ni) {
      const int n_abs = n0 + wc * 64 + ni * 16 + l15;
      const int nn = n_abs - 2560;
      const int h = nn >> 6, d = nn & 63;
      const float bv = bias[n_abs];
      u16* vrow = vt + ((size_t)(bbq * 20 + h) * 64 + d) * 2048;
#pragma unroll
      for (int mi = 0; mi < 2; ++mi) {
        const int ss = sbase + mi * 16 + lhi * 4;
        u16x4 pk = {f2bf(acc[mi][ni][0] + bv), f2bf(acc[mi][ni][1] + bv),
                    f2bf(acc[mi][ni][2] + bv), f2bf(acc[mi][ni][3] + bv)};
        *(u16x4*)(vrow + ss) = pk;
      }
    }
  }
}

// ---------------- proj GEMM: [4096,1280] x [1280,1280]^T + bias -> fp32 ----------------
// BM=64 (grid 64x10 = 640 blocks = 2.5/CU).
__global__ __launch_bounds__(256, 2) void k_gemm_proj(
    const u16* __restrict__ A, const u16* __restrict__ Bt,
    const float* __restrict__ bias, float* __restrict__ out) {
  constexpr int K = 1280;
  __shared__ u16 Alds[64 * 64];
  __shared__ u16 Blds[128 * 64];
  const int t = threadIdx.x;
  const int lane = t & 63, wave = t >> 6;
  const int wr = wave >> 1, wc = wave & 1;
  const int l15 = lane & 15, lhi = lane >> 4;
  const int m0 = blockIdx.x * 64, n0 = blockIdx.y * 128;

  f32x4 acc[2][4];
#pragma unroll
  for (int mi = 0; mi < 2; ++mi)
#pragma unroll
    for (int ni = 0; ni < 4; ++ni) acc[mi][ni] = f32x4{0.f, 0.f, 0.f, 0.f};

  const int srow = t >> 3;
  const int scol = (t & 7) * 8;
  const u16* Ag = A + (size_t)(m0 + srow) * K + scol;
  const u16* Bg = Bt + (size_t)(n0 + srow) * K + scol;
  char* Al = (char*)Alds + wave * 1024;
  char* Bl = (char*)Blds + wave * 1024;

  for (int k0 = 0; k0 < K; k0 += 64) {
    __syncthreads();
#pragma unroll
    for (int it = 0; it < 2; ++it)
      gload_lds16(Ag + (it * 32) * K + k0, Al + it * 4096);
#pragma unroll
    for (int it = 0; it < 4; ++it)
      gload_lds16(Bg + (it * 32) * K + k0, Bl + it * 4096);
    asm volatile("s_waitcnt vmcnt(0)" ::: "memory");
    __syncthreads();
    const u16* Ab = Alds + (wr * 32 + l15) * 64 + lhi * 8;
    const u16* Bb = Blds + (wc * 64 + l15) * 64 + lhi * 8;
    bf16x8 af[2][2], bfv[4][2];
#pragma unroll
    for (int x = 0; x < 2; ++x) {
      af[x][0] = *(const bf16x8*)(Ab + x * 1024);
      af[x][1] = *(const bf16x8*)(Ab + x * 1024 + 32);
    }
#pragma unroll
    for (int x = 0; x < 4; ++x) {
      bfv[x][0] = *(const bf16x8*)(Bb + x * 1024);
      bfv[x][1] = *(const bf16x8*)(Bb + x * 1024 + 32);
    }
#pragma unroll
    for (int mi = 0; mi < 2; ++mi)
#pragma unroll
      for (int ni = 0; ni < 4; ++ni) {
        acc[mi][ni] = MFMA16(af[mi][0], bfv[ni][0], acc[mi][ni], 0, 0, 0);
        acc[mi][ni] = MFMA16(af[mi][1], bfv[ni][1], acc[mi][ni], 0, 0, 0);
      }
  }

#pragma unroll
  for (int ni = 0; ni < 4; ++ni) {
    const int n_abs = n0 + wc * 64 + ni * 16 + l15;
    const float bv = bias[n_abs];
#pragma unroll
    for (int mi = 0; mi < 2; ++mi) {
#pragma unroll
      for (int i = 0; i < 4; ++i) {
        const int m_abs = m0 + wr * 32 + mi * 16 + lhi * 4 + i;
        out[(size_t)m_abs * 1280 + n_abs] = acc[mi][ni][i] + bv;
      }
    }
  }
}

// ---------------- causal flash attention v11 (champion config) ----------------
__global__ __launch_bounds__(256, 3) void k_attn11(
    const u16* __restrict__ Qg, const u16* __restrict__ Kg,
    const u16* __restrict__ VT, u16* __restrict__ ao) {
  __shared__ __align__(16) char kvs[2][16384];   // [buf][K 8KB | V 8KB]
  __shared__ u16 Plds[4][32 * 72];
  const int t = threadIdx.x;
  const int lane = t & 63, wave = t >> 6;
  const int l15 = lane & 15, lhi = lane >> 4;
  const int bh = blockIdx.x;
  const int qt = 15 - blockIdx.y;          // longest-first
  const int bb = bh / 20, hh = bh % 20;
  const int q0w = qt * 128 + wave * 32;
  const int nkv = 2 * (qt + 1);
  const size_t base = (size_t)bh * 2048 * 64;
  const size_t vtb = (size_t)bh * 64 * 2048;
  u16* Pw = Plds[wave];

  const int sls = (lane & 7) ^ (lane >> 3);
  const int soff0 = ((lhi ^ (lane & 7)) << 4);
  const int soff1 = (((4 + lhi) ^ (lane & 7)) << 4);

  bf16x8 qf[2][2];
#pragma unroll
  for (int mr = 0; mr < 2; ++mr)
#pragma unroll
    for (int kk = 0; kk < 2; ++kk)
      qf[mr][kk] = *(const bf16x8*)(Qg + base + (size_t)(q0w + mr * 16 + l15) * 64 + kk * 32 + lhi * 8);

  f32x4 o[2][4];
  float lp[2][4];
#pragma unroll
  for (int mr = 0; mr < 2; ++mr) {
#pragma unroll
    for (int i = 0; i < 4; ++i) lp[mr][i] = 0.f;
#pragma unroll
    for (int dc = 0; dc < 4; ++dc) o[mr][dc] = f32x4{0.f, 0.f, 0.f, 0.f};
  }
  const float c1 = 0.18033688f;            // 0.125 * log2(e)
  const float M = 16.0f;                   // fixed shift (exp2 domain)
  const int lastw = (q0w + 31) >> 6;

  auto stage = [&](char* buf, int kv0) {
#pragma unroll
    for (int j = 0; j < 2; ++j) {
      const int r = j * 32 + wave * 8 + (lane >> 3);
      gload_lds16(Kg + base + (size_t)(kv0 + r) * 64 + sls * 8,
                  buf + j * 4096 + wave * 1024);
      gload_lds16(VT + vtb + (size_t)r * 2048 + kv0 + sls * 8,
                  buf + 8192 + j * 4096 + wave * 1024);
    }
  };

  stage(kvs[0], 0);                        // prologue

  for (int tk = 0; tk < nkv; ++tk) {
    const int kv0 = tk * 64;
    if (tk + 1 < nkv) {
      stage(kvs[(tk + 1) & 1], kv0 + 64);  // issue next BEFORE waiting
      asm volatile("s_waitcnt vmcnt(4)" ::: "memory");
    } else {
      asm volatile("s_waitcnt vmcnt(0)" ::: "memory");
    }
    __syncthreads();

    if (tk <= lastw) {
      const char* Krow = kvs[tk & 1] + l15 * 128;
      const char* Vrow = kvs[tk & 1] + 8192 + l15 * 128;
      f32x4 sc[2][4];
#pragma unroll
      for (int c = 0; c < 4; ++c) {
        const bf16x8 kf0 = *(const bf16x8*)(Krow + c * 2048 + soff0);
        const bf16x8 kf1 = *(const bf16x8*)(Krow + c * 2048 + soff1);
#pragma unroll
        for (int mr = 0; mr < 2; ++mr) {
          f32x4 z = MFMA16(qf[mr][0], kf0, f32x4{0.f, 0.f, 0.f, 0.f}, 0, 0, 0);
          z = MFMA16(qf[mr][1], kf1, z, 0, 0, 0);
          sc[mr][c] = z;
        }
      }
      if (kv0 + 63 > q0w) {
#pragma unroll
        for (int mr = 0; mr < 2; ++mr)
#pragma unroll
          for (int c = 0; c < 4; ++c)
#pragma unroll
            for (int i = 0; i < 4; ++i) {
              const int qa = q0w + mr * 16 + lhi * 4 + i;
              const int ka = kv0 + c * 16 + l15;
              sc[mr][c][i] = (ka <= qa) ? sc[mr][c][i] : -3.0e38f;
            }
      }
#pragma unroll
      for (int mr = 0; mr < 2; ++mr)
#pragma unroll
        for (int i = 0; i < 4; ++i) {
          float psum = 0.f;
#pragma unroll
          for (int c = 0; c < 4; ++c) {
            const float p = vexp2(__builtin_fmaf(sc[mr][c][i], c1, -M));
            psum += p;
            Pw[(mr * 16 + lhi * 4 + i) * 72 + c * 16 + l15] = (u16)(__float_as_uint(p) >> 16);
          }
          lp[mr][i] += psum;
        }
      bf16x8 pf[2][2];
#pragma unroll
      for (int mr = 0; mr < 2; ++mr)
#pragma unroll
        for (int kk = 0; kk < 2; ++kk)
          pf[mr][kk] = *(const bf16x8*)&Pw[(mr * 16 + l15) * 72 + kk * 32 + lhi * 8];
#pragma unroll
      for (int dc = 0; dc < 4; ++dc) {
        const bf16x8 vf0 = *(const bf16x8*)(Vrow + dc * 2048 + soff0);
        const bf16x8 vf1 = *(const bf16x8*)(Vrow + dc * 2048 + soff1);
#pragma unroll
        for (int mr = 0; mr < 2; ++mr) {
          o[mr][dc] = MFMA16(pf[mr][0], vf0, o[mr][dc], 0, 0, 0);
          o[mr][dc] = MFMA16(pf[mr][1], vf1, o[mr][dc], 0, 0, 0);
        }
      }
    }
    __syncthreads();
  }

#pragma unroll
  for (int mr = 0; mr < 2; ++mr)
#pragma unroll
    for (int i = 0; i < 4; ++i) {
      const float lfull = rowsum16(lp[mr][i]);
      const float inv = 1.0f / lfull;
      const int qa = q0w + mr * 16 + lhi * 4 + i;
#pragma unroll
      for (int dc = 0; dc < 4; ++dc) {
        const int d = dc * 16 + l15;
        ao[((size_t)(bb * 2048 + qa)) * 1280 + hh * 64 + d] = f2bf(o[mr][dc][i] * inv);
      }
    }
}

extern "C" void kernel_launch(void* const* d_in, const int* in_sizes, int n_in,
                              void* d_out, int out_size, void* d_ws, size_t ws_size,
                              hipStream_t stream) {
  (void)in_sizes; (void)n_in; (void)out_size; (void)ws_size;
  const float* x      = (const float*)d_in[0];
  const float* w_attn = (const float*)d_in[1];
  const float* b_attn = (const float*)d_in[2];
  const float* w_proj = (const float*)d_in[3];
  const float* b_proj = (const float*)d_in[4];
  float* out = (float*)d_out;

  char* ws = (char*)d_ws;
  u16* x_bf = (u16*)(ws + 0);              // 10485760 B; reused as ao after gemm_qkv
  u16* wa_t = (u16*)(ws + 10485760);       //  9830400 B
  u16* wp_t = (u16*)(ws + 20316160);       //  3276800 B
  u16* q_ws = (u16*)(ws + 23592960);       // 10485760 B
  u16* k_ws = (u16*)(ws + 34078720);       // 10485760 B
  u16* vt   = (u16*)(ws + 44564480);       // 10485760 B; VT written directly by gemm_qkv
  u16* ao   = x_bf;

  k_prep<<<6720, 256, 0, stream>>>(x, x_bf, w_attn, wa_t, w_proj, wp_t);
  k_gemm_qkv<<<dim3(64, 30), 256, 0, stream>>>(x_bf, wa_t, b_attn, q_ws, k_ws, vt);
  k_attn11<<<dim3(40, 16), 256, 0, stream>>>(q_ws, k_ws, vt, ao);
  k_gemm_proj<<<dim3(64, 10), 256, 0, stream>>>(ao, wp_t, b_proj, out);
}

// Round 20
// 137.673 us; speedup vs baseline: 1.1449x; 1.1449x over previous
//
#include <hip/hip_runtime.h>

typedef unsigned short u16;
typedef __attribute__((ext_vector_type(8))) short bf16x8;
typedef __attribute__((ext_vector_type(4))) float f32x4;
typedef __attribute__((ext_vector_type(4))) unsigned short u16x4;

#define MFMA16 __builtin_amdgcn_mfma_f32_16x16x32_bf16

__device__ __forceinline__ u16 f2bf(float f) {
  unsigned int u = __float_as_uint(f);
  u += 0x7fff + ((u >> 16) & 1);          // round-to-nearest-even
  return (u16)(u >> 16);
}

__device__ __forceinline__ float vexp2(float x) {
  float r; asm("v_exp_f32 %0, %1" : "=v"(r) : "v"(x)); return r;
}

// DPP lane-permute within 16-lane rows (VALU-latency)
template<int CTRL>
__device__ __forceinline__ float dppf(float v) {
  return __int_as_float(__builtin_amdgcn_update_dpp(0, __float_as_int(v), CTRL, 0xF, 0xF, true));
}
__device__ __forceinline__ float rowsum16(float v) {
  v += dppf<0xB1>(v);
  v += dppf<0x4E>(v);
  v += dppf<0x141>(v);
  v += dppf<0x140>(v);
  return v;
}

__device__ __forceinline__ void gload_lds16(const void* g, void* l) {
  __builtin_amdgcn_global_load_lds((__attribute__((address_space(1))) void*)g,
                                   (__attribute__((address_space(3))) void*)l,
                                   16, 0, 0);
}

// ---------------- fused prep: cast x + transpose both weights ----------------
// blocks [0,5120): cast x fp32->bf16 (4 elems/thread)
// blocks [5120,6320): transpose+cast w_attn [1280][3840] -> wa_t [3840][1280]
// blocks [6320,6720): transpose+cast w_proj [1280][1280] -> wp_t [1280][1280]
__global__ void k_prep(const float* __restrict__ x, u16* __restrict__ x_bf,
                       const float* __restrict__ w_attn, u16* __restrict__ wa_t,
                       const float* __restrict__ w_proj, u16* __restrict__ wp_t) {
  __shared__ float tile[64][65];
  const int blk = blockIdx.x;
  const int t = threadIdx.x;
  if (blk < 5120) {
    const int i = blk * 256 + t;
    const float4 v = reinterpret_cast<const float4*>(x)[i];
    u16x4 o = {f2bf(v.x), f2bf(v.y), f2bf(v.z), f2bf(v.w)};
    reinterpret_cast<u16x4*>(x_bf)[i] = o;
    return;
  }
  const float* src;
  u16* dst;
  int R, C, c0, r0;
  if (blk < 6320) {
    const int id = blk - 5120;
    src = w_attn; dst = wa_t; R = 1280; C = 3840;
    c0 = (id % 60) * 64; r0 = (id / 60) * 64;
  } else {
    const int id = blk - 6320;
    src = w_proj; dst = wp_t; R = 1280; C = 1280;
    c0 = (id % 20) * 64; r0 = (id / 20) * 64;
  }
#pragma unroll
  for (int i = 0; i < 16; ++i) {
    int e = i * 256 + t;
    int r = e >> 6, c = e & 63;
    tile[r][c] = src[(size_t)(r0 + r) * C + (c0 + c)];
  }
  __syncthreads();
#pragma unroll
  for (int i = 0; i < 16; ++i) {
    int e = i * 256 + t;
    int r = e >> 6, c = e & 63;
    dst[(size_t)(c0 + r) * R + (r0 + c)] = f2bf(tile[c][r]);
  }
}

// ---------------- qkv GEMM: [4096,1280] x [3840,1280]^T + bias ----------------
// Q,K written as [bh][s][64]; V written TRANSPOSED as VT [bh][d][2048].
// Single-buffer 2-barrier K-loop (champion config).
__global__ __launch_bounds__(256, 2) void k_gemm_qkv(
    const u16* __restrict__ A, const u16* __restrict__ Bt,
    const float* __restrict__ bias,
    u16* __restrict__ qo, u16* __restrict__ ko, u16* __restrict__ vt) {
  constexpr int K = 1280;
  __shared__ u16 Alds[128 * 64];
  __shared__ u16 Blds[128 * 64];
  const int t = threadIdx.x;
  const int lane = t & 63, wave = t >> 6;
  const int wr = wave >> 1, wc = wave & 1;
  const int l15 = lane & 15, lhi = lane >> 4;
  const int m0 = blockIdx.x * 128, n0 = blockIdx.y * 128;

  f32x4 acc[4][4];
#pragma unroll
  for (int mi = 0; mi < 4; ++mi)
#pragma unroll
    for (int ni = 0; ni < 4; ++ni) acc[mi][ni] = f32x4{0.f, 0.f, 0.f, 0.f};

  const int srow = t >> 3;
  const int scol = (t & 7) * 8;
  const u16* Ag = A + (size_t)(m0 + srow) * K + scol;
  const u16* Bg = Bt + (size_t)(n0 + srow) * K + scol;
  char* Al = (char*)Alds + wave * 1024;
  char* Bl = (char*)Blds + wave * 1024;

  for (int k0 = 0; k0 < K; k0 += 64) {
    __syncthreads();
#pragma unroll
    for (int it = 0; it < 4; ++it) {
      gload_lds16(Ag + (it * 32) * K + k0, Al + it * 4096);
      gload_lds16(Bg + (it * 32) * K + k0, Bl + it * 4096);
    }
    asm volatile("s_waitcnt vmcnt(0)" ::: "memory");
    __syncthreads();
    const u16* Ab = Alds + (wr * 64 + l15) * 64 + lhi * 8;
    const u16* Bb = Blds + (wc * 64 + l15) * 64 + lhi * 8;
    bf16x8 af[4][2], bfv[4][2];
#pragma unroll
    for (int x = 0; x < 4; ++x) {
      af[x][0] = *(const bf16x8*)(Ab + x * 1024);
      af[x][1] = *(const bf16x8*)(Ab + x * 1024 + 32);
      bfv[x][0] = *(const bf16x8*)(Bb + x * 1024);
      bfv[x][1] = *(const bf16x8*)(Bb + x * 1024 + 32);
    }
#pragma unroll
    for (int mi = 0; mi < 4; ++mi)
#pragma unroll
      for (int ni = 0; ni < 4; ++ni) {
        acc[mi][ni] = MFMA16(af[mi][0], bfv[ni][0], acc[mi][ni], 0, 0, 0);
        acc[mi][ni] = MFMA16(af[mi][1], bfv[ni][1], acc[mi][ni], 0, 0, 0);
      }
  }

  const int which = n0 >= 2560 ? 2 : (n0 >= 1280 ? 1 : 0);
  const int bbq = m0 >> 11;                // batch index (constant per block)
  const int sbase = (m0 & 2047) + wr * 64; // s offset of this wave's rows
  if (which < 2) {
    u16* outp = which == 0 ? qo : ko;
#pragma unroll
    for (int ni = 0; ni < 4; ++ni) {
      const int n_abs = n0 + wc * 64 + ni * 16 + l15;
      const int nn = n_abs - which * 1280;
      const int h = nn >> 6, d = nn & 63;
      const float bv = bias[n_abs];
#pragma unroll
      for (int mi = 0; mi < 4; ++mi) {
#pragma unroll
        for (int i = 0; i < 4; ++i) {
          const int ss = sbase + mi * 16 + lhi * 4 + i;
          outp[(((size_t)(bbq * 20 + h) * 2048 + ss) << 6) + d] = f2bf(acc[mi][ni][i] + bv);
        }
      }
    }
  } else {
    // V: write transposed VT[(bb*20+h)*64 + d][s], 4 consecutive s -> 8B store
#pragma unroll
    for (int ni = 0; ni < 4; ++ni) {
      const int n_abs = n0 + wc * 64 + ni * 16 + l15;
      const int nn = n_abs - 2560;
      const int h = nn >> 6, d = nn & 63;
      const float bv = bias[n_abs];
      u16* vrow = vt + ((size_t)(bbq * 20 + h) * 64 + d) * 2048;
#pragma unroll
      for (int mi = 0; mi < 4; ++mi) {
        const int ss = sbase + mi * 16 + lhi * 4;
        u16x4 pk = {f2bf(acc[mi][ni][0] + bv), f2bf(acc[mi][ni][1] + bv),
                    f2bf(acc[mi][ni][2] + bv), f2bf(acc[mi][ni][3] + bv)};
        *(u16x4*)(vrow + ss) = pk;
      }
    }
  }
}

// ---------------- proj GEMM: [4096,1280] x [1280,1280]^T + bias -> fp32 ----------------
// BM=64 (grid 64x10 = 640 blocks = 2.5/CU) to fix grid starvation.
__global__ __launch_bounds__(256, 2) void k_gemm_proj(
    const u16* __restrict__ A, const u16* __restrict__ Bt,
    const float* __restrict__ bias, float* __restrict__ out) {
  constexpr int K = 1280;
  __shared__ u16 Alds[64 * 64];
  __shared__ u16 Blds[128 * 64];
  const int t = threadIdx.x;
  const int lane = t & 63, wave = t >> 6;
  const int wr = wave >> 1, wc = wave & 1;
  const int l15 = lane & 15, lhi = lane >> 4;
  const int m0 = blockIdx.x * 64, n0 = blockIdx.y * 128;

  f32x4 acc[2][4];
#pragma unroll
  for (int mi = 0; mi < 2; ++mi)
#pragma unroll
    for (int ni = 0; ni < 4; ++ni) acc[mi][ni] = f32x4{0.f, 0.f, 0.f, 0.f};

  const int srow = t >> 3;
  const int scol = (t & 7) * 8;
  const u16* Ag = A + (size_t)(m0 + srow) * K + scol;
  const u16* Bg = Bt + (size_t)(n0 + srow) * K + scol;
  char* Al = (char*)Alds + wave * 1024;
  char* Bl = (char*)Blds + wave * 1024;

  for (int k0 = 0; k0 < K; k0 += 64) {
    __syncthreads();
#pragma unroll
    for (int it = 0; it < 2; ++it)
      gload_lds16(Ag + (it * 32) * K + k0, Al + it * 4096);
#pragma unroll
    for (int it = 0; it < 4; ++it)
      gload_lds16(Bg + (it * 32) * K + k0, Bl + it * 4096);
    asm volatile("s_waitcnt vmcnt(0)" ::: "memory");
    __syncthreads();
    const u16* Ab = Alds + (wr * 32 + l15) * 64 + lhi * 8;
    const u16* Bb = Blds + (wc * 64 + l15) * 64 + lhi * 8;
    bf16x8 af[2][2], bfv[4][2];
#pragma unroll
    for (int x = 0; x < 2; ++x) {
      af[x][0] = *(const bf16x8*)(Ab + x * 1024);
      af[x][1] = *(const bf16x8*)(Ab + x * 1024 + 32);
    }
#pragma unroll
    for (int x = 0; x < 4; ++x) {
      bfv[x][0] = *(const bf16x8*)(Bb + x * 1024);
      bfv[x][1] = *(const bf16x8*)(Bb + x * 1024 + 32);
    }
#pragma unroll
    for (int mi = 0; mi < 2; ++mi)
#pragma unroll
      for (int ni = 0; ni < 4; ++ni) {
        acc[mi][ni] = MFMA16(af[mi][0], bfv[ni][0], acc[mi][ni], 0, 0, 0);
        acc[mi][ni] = MFMA16(af[mi][1], bfv[ni][1], acc[mi][ni], 0, 0, 0);
      }
  }

#pragma unroll
  for (int ni = 0; ni < 4; ++ni) {
    const int n_abs = n0 + wc * 64 + ni * 16 + l15;
    const float bv = bias[n_abs];
#pragma unroll
    for (int mi = 0; mi < 2; ++mi) {
#pragma unroll
      for (int i = 0; i < 4; ++i) {
        const int m_abs = m0 + wr * 32 + mi * 16 + lhi * 4 + i;
        out[(size_t)m_abs * 1280 + n_abs] = acc[mi][ni][i] + bv;
      }
    }
  }
}

// ---------------- causal flash attention v11 (champion config) ----------------
// grid (bh=40, qt16=16 longest-first) -> bh%8 XCD L2 affinity (40 = 0 mod 8).
// Fixed softmax shift M=16 (exp2 domain); both-sides XOR swizzle on KV staging.
__global__ __launch_bounds__(256, 3) void k_attn11(
    const u16* __restrict__ Qg, const u16* __restrict__ Kg,
    const u16* __restrict__ VT, u16* __restrict__ ao) {
  __shared__ __align__(16) char kvs[2][16384];   // [buf][K 8KB | V 8KB]
  __shared__ u16 Plds[4][32 * 72];
  const int t = threadIdx.x;
  const int lane = t & 63, wave = t >> 6;
  const int l15 = lane & 15, lhi = lane >> 4;
  const int bh = blockIdx.x;
  const int qt = 15 - blockIdx.y;          // longest-first
  const int bb = bh / 20, hh = bh % 20;
  const int q0w = qt * 128 + wave * 32;
  const int nkv = 2 * (qt + 1);
  const size_t base = (size_t)bh * 2048 * 64;
  const size_t vtb = (size_t)bh * 64 * 2048;
  u16* Pw = Plds[wave];

  // swizzled per-lane source column (16B slot) and reader slot offsets
  const int sls = (lane & 7) ^ (lane >> 3);
  const int soff0 = ((lhi ^ (lane & 7)) << 4);
  const int soff1 = (((4 + lhi) ^ (lane & 7)) << 4);

  // Q fragments in registers for the whole kernel
  bf16x8 qf[2][2];
#pragma unroll
  for (int mr = 0; mr < 2; ++mr)
#pragma unroll
    for (int kk = 0; kk < 2; ++kk)
      qf[mr][kk] = *(const bf16x8*)(Qg + base + (size_t)(q0w + mr * 16 + l15) * 64 + kk * 32 + lhi * 8);

  f32x4 o[2][4];
  float lp[2][4];                          // per-lane partial sums (no rescale needed)
#pragma unroll
  for (int mr = 0; mr < 2; ++mr) {
#pragma unroll
    for (int i = 0; i < 4; ++i) lp[mr][i] = 0.f;
#pragma unroll
    for (int dc = 0; dc < 4; ++dc) o[mr][dc] = f32x4{0.f, 0.f, 0.f, 0.f};
  }
  const float c1 = 0.18033688f;            // 0.125 * log2(e)
  const float M = 16.0f;                   // fixed shift (exp2 domain); 11-sigma headroom
  const int lastw = (q0w + 31) >> 6;

  // ---- stage helper: 4 gload_lds16 per thread per tile ----
  auto stage = [&](char* buf, int kv0) {
#pragma unroll
    for (int j = 0; j < 2; ++j) {
      const int r = j * 32 + wave * 8 + (lane >> 3);
      gload_lds16(Kg + base + (size_t)(kv0 + r) * 64 + sls * 8,
                  buf + j * 4096 + wave * 1024);
      gload_lds16(VT + vtb + (size_t)r * 2048 + kv0 + sls * 8,
                  buf + 8192 + j * 4096 + wave * 1024);
    }
  };

  stage(kvs[0], 0);                        // prologue

  for (int tk = 0; tk < nkv; ++tk) {
    const int kv0 = tk * 64;
    if (tk + 1 < nkv) {
      stage(kvs[(tk + 1) & 1], kv0 + 64);  // issue next BEFORE waiting (T3/T4)
      asm volatile("s_waitcnt vmcnt(4)" ::: "memory");
    } else {
      asm volatile("s_waitcnt vmcnt(0)" ::: "memory");
    }
    __syncthreads();

    if (tk <= lastw) {                     // wave-uniform: skip fully-masked tiles
      const char* Krow = kvs[tk & 1] + l15 * 128;
      const char* Vrow = kvs[tk & 1] + 8192 + l15 * 128;
      // ---- S = Q K^T ----
      f32x4 sc[2][4];
#pragma unroll
      for (int c = 0; c < 4; ++c) {
        const bf16x8 kf0 = *(const bf16x8*)(Krow + c * 2048 + soff0);
        const bf16x8 kf1 = *(const bf16x8*)(Krow + c * 2048 + soff1);
#pragma unroll
        for (int mr = 0; mr < 2; ++mr) {
          f32x4 z = MFMA16(qf[mr][0], kf0, f32x4{0.f, 0.f, 0.f, 0.f}, 0, 0, 0);
          z = MFMA16(qf[mr][1], kf1, z, 0, 0, 0);
          sc[mr][c] = z;
        }
      }
      // ---- causal mask only near the diagonal ----
      if (kv0 + 63 > q0w) {
#pragma unroll
        for (int mr = 0; mr < 2; ++mr)
#pragma unroll
          for (int c = 0; c < 4; ++c)
#pragma unroll
            for (int i = 0; i < 4; ++i) {
              const int qa = q0w + mr * 16 + lhi * 4 + i;
              const int ka = kv0 + c * 16 + l15;
              sc[mr][c][i] = (ka <= qa) ? sc[mr][c][i] : -3.0e38f;
            }
      }
      // ---- p = exp2(s*c1 - M); per-lane partial sums; P -> LDS (truncate bf16) ----
#pragma unroll
      for (int mr = 0; mr < 2; ++mr)
#pragma unroll
        for (int i = 0; i < 4; ++i) {
          float psum = 0.f;
#pragma unroll
          for (int c = 0; c < 4; ++c) {
            const float p = vexp2(__builtin_fmaf(sc[mr][c][i], c1, -M));
            psum += p;
            Pw[(mr * 16 + lhi * 4 + i) * 72 + c * 16 + l15] = (u16)(__float_as_uint(p) >> 16);
          }
          lp[mr][i] += psum;
        }
      // ---- O += P V ----
      bf16x8 pf[2][2];
#pragma unroll
      for (int mr = 0; mr < 2; ++mr)
#pragma unroll
        for (int kk = 0; kk < 2; ++kk)
          pf[mr][kk] = *(const bf16x8*)&Pw[(mr * 16 + l15) * 72 + kk * 32 + lhi * 8];
#pragma unroll
      for (int dc = 0; dc < 4; ++dc) {
        const bf16x8 vf0 = *(const bf16x8*)(Vrow + dc * 2048 + soff0);
        const bf16x8 vf1 = *(const bf16x8*)(Vrow + dc * 2048 + soff1);
#pragma unroll
        for (int mr = 0; mr < 2; ++mr) {
          o[mr][dc] = MFMA16(pf[mr][0], vf0, o[mr][dc], 0, 0, 0);
          o[mr][dc] = MFMA16(pf[mr][1], vf1, o[mr][dc], 0, 0, 0);
        }
      }
    }
    __syncthreads();
  }

  // ---- epilogue: complete l (DPP), divide, store ----
#pragma unroll
  for (int mr = 0; mr < 2; ++mr)
#pragma unroll
    for (int i = 0; i < 4; ++i) {
      const float lfull = rowsum16(lp[mr][i]);
      const float inv = 1.0f / lfull;
      const int qa = q0w + mr * 16 + lhi * 4 + i;
#pragma unroll
      for (int dc = 0; dc < 4; ++dc) {
        const int d = dc * 16 + l15;
        ao[((size_t)(bb * 2048 + qa)) * 1280 + hh * 64 + d] = f2bf(o[mr][dc][i] * inv);
      }
    }
}

extern "C" void kernel_launch(void* const* d_in, const int* in_sizes, int n_in,
                              void* d_out, int out_size, void* d_ws, size_t ws_size,
                              hipStream_t stream) {
  (void)in_sizes; (void)n_in; (void)out_size; (void)ws_size;
  const float* x      = (const float*)d_in[0];
  const float* w_attn = (const float*)d_in[1];
  const float* b_attn = (const float*)d_in[2];
  const float* w_proj = (const float*)d_in[3];
  const float* b_proj = (const float*)d_in[4];
  float* out = (float*)d_out;

  char* ws = (char*)d_ws;
  u16* x_bf = (u16*)(ws + 0);              // 10485760 B; reused as ao after gemm_qkv
  u16* wa_t = (u16*)(ws + 10485760);       //  9830400 B
  u16* wp_t = (u16*)(ws + 20316160);       //  3276800 B
  u16* q_ws = (u16*)(ws + 23592960);       // 10485760 B
  u16* k_ws = (u16*)(ws + 34078720);       // 10485760 B
  u16* vt   = (u16*)(ws + 44564480);       // 10485760 B; VT written directly by gemm_qkv
  u16* ao   = x_bf;

  k_prep<<<6720, 256, 0, stream>>>(x, x_bf, w_attn, wa_t, w_proj, wp_t);
  k_gemm_qkv<<<dim3(32, 30), 256, 0, stream>>>(x_bf, wa_t, b_attn, q_ws, k_ws, vt);
  k_attn11<<<dim3(40, 16), 256, 0, stream>>>(q_ws, k_ws, vt, ao);
  k_gemm_proj<<<dim3(64, 10), 256, 0, stream>>>(ao, wp_t, b_proj, out);
}